// Round 7
// baseline (584.357 us; speedup 1.0000x reference)
//
#include <hip/hip_runtime.h>
#include <hip/hip_bf16.h>
#include <cmath>

typedef __bf16 bf16;
typedef __attribute__((ext_vector_type(8))) __bf16 bf16x8;
typedef __attribute__((ext_vector_type(4))) __bf16 bf16x4;
typedef __attribute__((ext_vector_type(4))) float f32x4;
typedef __attribute__((ext_vector_type(4))) unsigned int u32x4;

#define LD_B 2
#define LD_L 2048
#define LD_D 512
#define N_HEAD 8
#define HD 64
#define NTOK (LD_B * LD_L)  // 4096
#define QKV_LD 1536         // fused QKV row stride

// ======== MEASUREMENT ROUND: internal repeat loops to surface per-kernel ====
// ======== durations above the 42us fillBuffer rows in the rocprof top-5. ====
// ======== True per-kernel cost = reported dur / REP_*. Revert next round. ===
#define REP_GEMM 16
#define REP_ATTN 16
#define REP_PREP 16
#define REP_LN   64

__device__ __forceinline__ void gload16(const void* g, void* l) {
  __builtin_amdgcn_global_load_lds(
      (const __attribute__((address_space(1))) void*)g,
      (__attribute__((address_space(3))) void*)l, 16, 0, 0);
}

// ------------- prep: LN1 (blocks 0..1023) + weight cast (blocks 1024..3071) --
__global__ __launch_bounds__(256) void prep_kernel(
    const float* __restrict__ x, const float* __restrict__ g,
    const float* __restrict__ b, bf16* __restrict__ xln,
    const float* __restrict__ s0, const float* __restrict__ s1,
    const float* __restrict__ s2, const float* __restrict__ s3,
    const float* __restrict__ s4, const float* __restrict__ s5,
    bf16* __restrict__ d0, bf16* __restrict__ d1, bf16* __restrict__ d2,
    bf16* __restrict__ d3, bf16* __restrict__ d4, bf16* __restrict__ d5)
{
  for (int rp = 0; rp < REP_PREP; ++rp) {
    if (blockIdx.x >= 1024) {
      int idx = (blockIdx.x - 1024) * 256 + threadIdx.x;  // 0..524287
      const float* src; bf16* dst; int off;
      if (idx < 262144) {
        int seg = idx >> 16; off = idx & 65535;
        src = seg == 0 ? s0 : seg == 1 ? s1 : seg == 2 ? s2 : s3;
        dst = seg == 0 ? d0 : seg == 1 ? d1 : seg == 2 ? d2 : d3;
      } else {
        int t = idx - 262144;
        int seg = t >> 17; off = t & 131071;
        src = seg ? s5 : s4;
        dst = seg ? d5 : d4;
      }
      f32x4 v = ((const f32x4*)src)[off];
      bf16x4 o;
      o[0] = (bf16)v[0]; o[1] = (bf16)v[1]; o[2] = (bf16)v[2]; o[3] = (bf16)v[3];
      ((bf16x4*)dst)[off] = o;
      continue;
    }
    const int wid = threadIdx.x >> 6, lane = threadIdx.x & 63;
    const int row = blockIdx.x * 4 + wid;
    const f32x4* xr = (const f32x4*)(x + (size_t)row * LD_D);
    f32x4 v0 = xr[lane * 2], v1 = xr[lane * 2 + 1];
    float s = v0[0] + v0[1] + v0[2] + v0[3] + v1[0] + v1[1] + v1[2] + v1[3];
#pragma unroll
    for (int off = 32; off; off >>= 1) s += __shfl_xor(s, off);
    const float mu = s * (1.f / 512.f);
    float vs = 0.f;
#pragma unroll
    for (int i = 0; i < 4; ++i) {
      float a0 = v0[i] - mu; vs += a0 * a0;
      float a1 = v1[i] - mu; vs += a1 * a1;
    }
#pragma unroll
    for (int off = 32; off; off >>= 1) vs += __shfl_xor(vs, off);
    const float rstd = rsqrtf(vs * (1.f / 512.f) + 1e-5f);
    const f32x4* gr = (const f32x4*)g;
    const f32x4* br = (const f32x4*)b;
    f32x4 g0 = gr[lane * 2], g1 = gr[lane * 2 + 1];
    f32x4 b0 = br[lane * 2], b1 = br[lane * 2 + 1];
    bf16x8 o;
#pragma unroll
    for (int i = 0; i < 4; ++i) o[i] = (bf16)((v0[i] - mu) * rstd * g0[i] + b0[i]);
#pragma unroll
    for (int i = 0; i < 4; ++i) o[i + 4] = (bf16)((v1[i] - mu) * rstd * g1[i] + b1[i]);
    *(bf16x8*)(&xln[(size_t)row * LD_D + lane * 8]) = o;
  }
}

// ---------------- layernorm (fp32 in, bf16 out), one wave per 512-row -------
__global__ __launch_bounds__(256) void ln_kernel(
    const float* __restrict__ x, const float* __restrict__ g,
    const float* __restrict__ b, bf16* __restrict__ out)
{
  for (int rp = 0; rp < REP_LN; ++rp) {
    const int wid = threadIdx.x >> 6, lane = threadIdx.x & 63;
    const int row = blockIdx.x * 4 + wid;
    const f32x4* xr = (const f32x4*)(x + (size_t)row * LD_D);
    f32x4 v0 = xr[lane * 2], v1 = xr[lane * 2 + 1];
    float s = v0[0] + v0[1] + v0[2] + v0[3] + v1[0] + v1[1] + v1[2] + v1[3];
#pragma unroll
    for (int off = 32; off; off >>= 1) s += __shfl_xor(s, off);
    const float mu = s * (1.f / 512.f);
    float vs = 0.f;
#pragma unroll
    for (int i = 0; i < 4; ++i) {
      float a0 = v0[i] - mu; vs += a0 * a0;
      float a1 = v1[i] - mu; vs += a1 * a1;
    }
#pragma unroll
    for (int off = 32; off; off >>= 1) vs += __shfl_xor(vs, off);
    const float rstd = rsqrtf(vs * (1.f / 512.f) + 1e-5f);
    const f32x4* gr = (const f32x4*)g;
    const f32x4* br = (const f32x4*)b;
    f32x4 g0 = gr[lane * 2], g1 = gr[lane * 2 + 1];
    f32x4 b0 = br[lane * 2], b1 = br[lane * 2 + 1];
    bf16x8 o;
#pragma unroll
    for (int i = 0; i < 4; ++i) o[i] = (bf16)((v0[i] - mu) * rstd * g0[i] + b0[i]);
#pragma unroll
    for (int i = 0; i < 4; ++i) o[i + 4] = (bf16)((v1[i] - mu) * rstd * g1[i] + b1[i]);
    *(bf16x8*)(&out[(size_t)row * LD_D + lane * 8]) = o;
  }
}

// ---------------- GEMM: C[M,N] = A[M,K] * Bw[N,K]^T, bf16 in, fp32 acc ------
// BM=BN=64 (r5-best geometry), BK=64, REP repeats of the compute phase.
template <int BM, int BN, int EPI, int REP>
__device__ __forceinline__ void gemm_core(
    const bf16* __restrict__ A, const bf16* __restrict__ Bw,
    int M, int N, int K, bf16* __restrict__ Cb, float* __restrict__ Cf,
    const float* __restrict__ bias, const float* __restrict__ res)
{
  constexpr int WM = BM / 2, WN = BN / 2;
  constexpr int FM = WM / 16, FN = WN / 16;
  constexpr int IA = BM / 32, IB = BN / 32;
  __shared__ bf16 As[2][BM * 64];
  __shared__ bf16 Bs[2][BN * 64];
  const int tid = threadIdx.x;
  const int lane = tid & 63, wid = tid >> 6;
  const int wm = wid >> 1, wn = wid & 1;
  const int l15 = lane & 15, kg = lane >> 4;
  const int row0 = blockIdx.x * BM, col0 = blockIdx.y * BN;

  int srowA[IA], scolA[IA];
#pragma unroll
  for (int i = 0; i < IA; ++i) {
    int c = i * 256 + tid;
    srowA[i] = c >> 3;
    scolA[i] = ((c & 7) ^ (srowA[i] & 7)) * 8;
  }
  int srowB[IB], scolB[IB];
#pragma unroll
  for (int i = 0; i < IB; ++i) {
    int c = i * 256 + tid;
    srowB[i] = c >> 3;
    scolB[i] = ((c & 7) ^ (srowB[i] & 7)) * 8;
  }

  f32x4 acc[FM][FN];
  const int nt = K >> 6;
  auto STAGE = [&](int buf, int k0) {
#pragma unroll
    for (int i = 0; i < IA; ++i) {
      const bf16* ga = A + (size_t)(row0 + srowA[i]) * K + k0 + scolA[i];
      char* la = (char*)&As[buf][0] + i * 4096 + wid * 1024;
      gload16(ga, la);
    }
#pragma unroll
    for (int i = 0; i < IB; ++i) {
      const bf16* gb = Bw + (size_t)(col0 + srowB[i]) * K + k0 + scolB[i];
      char* lb = (char*)&Bs[buf][0] + i * 4096 + wid * 1024;
      gload16(gb, lb);
    }
  };

  for (int rp = 0; rp < REP; ++rp) {
#pragma unroll
    for (int m = 0; m < FM; ++m)
#pragma unroll
      for (int n = 0; n < FN; ++n) acc[m][n] = (f32x4){0.f, 0.f, 0.f, 0.f};

    STAGE(0, 0);
    __syncthreads();
    for (int t = 0; t < nt; ++t) {
      if (t + 1 < nt) STAGE((t + 1) & 1, (t + 1) << 6);
      const char* pa = (const char*)&As[t & 1][0];
      const char* pb = (const char*)&Bs[t & 1][0];
#pragma unroll
      for (int kk = 0; kk < 2; ++kk) {
        bf16x8 af[FM], bf[FN];
#pragma unroll
        for (int m = 0; m < FM; ++m) {
          const int r = wm * WM + m * 16 + l15;
          int off = r * 128 + kk * 64 + kg * 16;
          off ^= (r & 7) << 4;
          af[m] = *(const bf16x8*)(pa + off);
        }
#pragma unroll
        for (int n = 0; n < FN; ++n) {
          const int r = wn * WN + n * 16 + l15;
          int off = r * 128 + kk * 64 + kg * 16;
          off ^= (r & 7) << 4;
          bf[n] = *(const bf16x8*)(pb + off);
        }
#pragma unroll
        for (int m = 0; m < FM; ++m)
#pragma unroll
          for (int n = 0; n < FN; ++n)
            acc[m][n] = __builtin_amdgcn_mfma_f32_16x16x32_bf16(af[m], bf[n], acc[m][n], 0, 0, 0);
      }
      __syncthreads();
    }
  }

  const int orow = row0 + wm * WM, ocol = col0 + wn * WN;
#pragma unroll
  for (int m = 0; m < FM; ++m) {
#pragma unroll
    for (int n = 0; n < FN; ++n) {
#pragma unroll
      for (int e = 0; e < 4; ++e) {
        const int rr = orow + m * 16 + kg * 4 + e;   // C/D: row=(lane>>4)*4+reg
        const int cc = ocol + n * 16 + l15;          //      col=lane&15
        const float v = acc[m][n][e];
        const size_t oi = (size_t)rr * N + cc;
        if constexpr (EPI == 0) {
          Cb[oi] = (bf16)v;
        } else if constexpr (EPI == 1) {
          Cf[oi] = v + res[oi];
        } else if constexpr (EPI == 2) {
          float t2 = v + bias[cc];
          Cb[oi] = (bf16)(0.5f * t2 * (1.f + erff(t2 * 0.70710678118654752f)));
        } else {
          Cf[oi] = v + bias[cc] + res[oi];
        }
      }
    }
  }
}

// named wrappers (unique profiler rows), r5-best 64x64 geometry
__global__ __launch_bounds__(256) void gemm_qkv(
    const bf16* __restrict__ A, const bf16* __restrict__ Bw,
    bf16* __restrict__ Cb)
{
  gemm_core<64, 64, 0, REP_GEMM>(A, Bw, NTOK, QKV_LD, 512, Cb, nullptr, nullptr, nullptr);
}
__global__ __launch_bounds__(256) void gemm_oproj(
    const bf16* __restrict__ A, const bf16* __restrict__ Bw,
    float* __restrict__ Cf, const float* __restrict__ res)
{
  gemm_core<64, 64, 1, REP_GEMM>(A, Bw, NTOK, 512, 512, nullptr, Cf, nullptr, res);
}
__global__ __launch_bounds__(256) void gemm_mlp1(
    const bf16* __restrict__ A, const bf16* __restrict__ Bw,
    bf16* __restrict__ Cb, const float* __restrict__ bias)
{
  gemm_core<64, 64, 2, REP_GEMM>(A, Bw, NTOK, 1024, 512, Cb, nullptr, bias, nullptr);
}
__global__ __launch_bounds__(256) void gemm_mlp2(
    const bf16* __restrict__ A, const bf16* __restrict__ Bw,
    float* __restrict__ Cf, const float* __restrict__ bias,
    const float* __restrict__ res)
{
  gemm_core<64, 64, 3, REP_GEMM>(A, Bw, NTOK, 512, 1024, nullptr, Cf, bias, res);
}

// ---------------- sliding-window causal attention, MFMA version -------------
__global__ __launch_bounds__(256) void attn_kernel(
    const bf16* __restrict__ QKV, bf16* __restrict__ Og)
{
  constexpr int STK = 72;
  constexpr int STP = 136;
  __shared__ bf16 Ks[128][STK];
  __shared__ bf16 Qs[64][STK];
  __shared__ bf16 Vt[64][STP];
  __shared__ bf16 Ps[4][16][STP];
  const int tid = threadIdx.x;
  const int qt = blockIdx.x, bh = blockIdx.y;
  const int b = bh >> 3, h = bh & 7;
  const int q0 = qt * 64;
  const int j0 = q0 - 63;
  const size_t baseQ = (size_t)b * LD_L * QKV_LD + h * HD;
  const size_t baseK = baseQ + 512;
  const size_t baseV = baseQ + 1024;
  const size_t baseO = (size_t)b * LD_L * LD_D + h * HD;

  for (int rp = 0; rp < REP_ATTN; ++rp) {
    __syncthreads();  // protect LDS from previous rep's readers
    for (int c = tid; c < 128 * 8; c += 256) {
      const int r = c >> 3, d0 = (c & 7) * 8;
      const int j = j0 + r;
      u32x4 kv = (u32x4){0u, 0u, 0u, 0u};
      bf16x8 vv = (bf16x8)(__bf16)0.f;
      if (j >= 0 && j < LD_L) {
        kv = *(const u32x4*)(QKV + baseK + (size_t)j * QKV_LD + d0);
        vv = *(const bf16x8*)(QKV + baseV + (size_t)j * QKV_LD + d0);
      }
      *(u32x4*)(&Ks[r][d0]) = kv;
#pragma unroll
      for (int dd = 0; dd < 8; ++dd) Vt[d0 + dd][r] = vv[dd];
    }
    for (int c = tid; c < 64 * 8; c += 256) {
      const int r = c >> 3, d0 = (c & 7) * 8;
      *(u32x4*)(&Qs[r][d0]) =
          *(const u32x4*)(QKV + baseQ + (size_t)(q0 + r) * QKV_LD + d0);
    }
    __syncthreads();

    const int lane = tid & 63, wid = tid >> 6;
    const int l15 = lane & 15, kg = lane >> 4;
    const int klo = 63 - q0;

    bf16x8 qf[2];
#pragma unroll
    for (int kk = 0; kk < 2; ++kk)
      qf[kk] = *(const bf16x8*)(&Qs[wid * 16 + l15][kk * 32 + kg * 8]);
    f32x4 s[8];
#pragma unroll
    for (int n = 0; n < 8; ++n) s[n] = (f32x4){0.f, 0.f, 0.f, 0.f};
#pragma unroll
    for (int kk = 0; kk < 2; ++kk)
#pragma unroll
      for (int n = 0; n < 8; ++n) {
        bf16x8 kf = *(const bf16x8*)(&Ks[n * 16 + l15][kk * 32 + kg * 8]);
        s[n] = __builtin_amdgcn_mfma_f32_16x16x32_bf16(qf[kk], kf, s[n], 0, 0, 0);
      }

    float p[8][4];
    float mx[4], sm[4];
#pragma unroll
    for (int e = 0; e < 4; ++e) { mx[e] = -INFINITY; sm[e] = 0.f; }
#pragma unroll
    for (int n = 0; n < 8; ++n) {
      const int k = n * 16 + l15;
#pragma unroll
      for (int e = 0; e < 4; ++e) {
        const int qi = wid * 16 + kg * 4 + e;
        const bool ok = (k >= qi) & (k <= qi + 63) & (k >= klo);
        float sv = ok ? s[n][e] * 0.125f : -INFINITY;
        p[n][e] = sv;
        mx[e] = fmaxf(mx[e], sv);
      }
    }
#pragma unroll
    for (int off = 8; off; off >>= 1)
#pragma unroll
      for (int e = 0; e < 4; ++e) mx[e] = fmaxf(mx[e], __shfl_xor(mx[e], off));
#pragma unroll
    for (int n = 0; n < 8; ++n)
#pragma unroll
      for (int e = 0; e < 4; ++e) {
        float pv = (p[n][e] == -INFINITY) ? 0.f : __expf(p[n][e] - mx[e]);
        p[n][e] = pv;
        sm[e] += pv;
      }
#pragma unroll
    for (int off = 8; off; off >>= 1)
#pragma unroll
      for (int e = 0; e < 4; ++e) sm[e] += __shfl_xor(sm[e], off);
    float rs[4];
#pragma unroll
    for (int e = 0; e < 4; ++e) rs[e] = 1.f / sm[e];

#pragma unroll
    for (int n = 0; n < 8; ++n)
#pragma unroll
      for (int e = 0; e < 4; ++e)
        Ps[wid][kg * 4 + e][n * 16 + l15] = (bf16)(p[n][e] * rs[e]);

    f32x4 o[4];
#pragma unroll
    for (int n = 0; n < 4; ++n) o[n] = (f32x4){0.f, 0.f, 0.f, 0.f};
#pragma unroll
    for (int ks = 0; ks < 4; ++ks) {
      bf16x8 pf = *(const bf16x8*)(&Ps[wid][l15][ks * 32 + kg * 8]);
#pragma unroll
      for (int n = 0; n < 4; ++n) {
        bf16x8 vf = *(const bf16x8*)(&Vt[n * 16 + l15][ks * 32 + kg * 8]);
        o[n] = __builtin_amdgcn_mfma_f32_16x16x32_bf16(pf, vf, o[n], 0, 0, 0);
      }
    }

    const int q = q0 + wid * 16 + kg * 4;
#pragma unroll
    for (int n = 0; n < 4; ++n)
#pragma unroll
      for (int e = 0; e < 4; ++e)
        Og[baseO + (size_t)(q + e) * LD_D + n * 16 + l15] = (bf16)o[n][e];
  }
}

// ---------------- launch ----------------
extern "C" void kernel_launch(void* const* d_in, const int* in_sizes, int n_in,
                              void* d_out, int out_size, void* d_ws, size_t ws_size,
                              hipStream_t stream)
{
  const float* query = (const float*)d_in[0];
  const float* ln_g = (const float*)d_in[1];
  const float* ln_b = (const float*)d_in[2];
  const float* wq = (const float*)d_in[3];
  const float* wk = (const float*)d_in[4];
  const float* wv = (const float*)d_in[5];
  const float* wo = (const float*)d_in[6];
  const float* w1 = (const float*)d_in[7];
  const float* b1 = (const float*)d_in[8];
  const float* w2 = (const float*)d_in[9];
  const float* b2 = (const float*)d_in[10];
  float* out = (float*)d_out;

  char* ws = (char*)d_ws;
  bf16* WQKVb = (bf16*)(ws + 0x000000);  // [1536][512] = 1.5MB
  bf16* WOb = (bf16*)(ws + 0x180000);    // 512KB
  bf16* W1b = (bf16*)(ws + 0x200000);    // 1MB
  bf16* W2b = (bf16*)(ws + 0x300000);    // 1MB
  bf16* XLN = (bf16*)(ws + 0x400000);    // 4MB
  bf16* QKVb = (bf16*)(ws + 0x800000);   // [4096][1536] = 12MB
  bf16* ATb = (bf16*)(ws + 0x1400000);   // 4MB
  float* Q2 = (float*)(ws + 0x1800000);  // 8MB
  bf16* YLN = (bf16*)(ws + 0x2000000);   // 4MB
  bf16* Hb = (bf16*)(ws + 0x2400000);    // 8MB (end 44MB)

  prep_kernel<<<3072, 256, 0, stream>>>(
      query, ln_g, ln_b, XLN,
      wq, wk, wv, wo, w1, w2,
      WQKVb, WQKVb + 262144, WQKVb + 524288, WOb, W1b, W2b);
  gemm_qkv<<<dim3(64, 24), 256, 0, stream>>>(XLN, WQKVb, QKVb);
  attn_kernel<<<dim3(32, 16), 256, 0, stream>>>(QKVb, ATb);
  gemm_oproj<<<dim3(64, 8), 256, 0, stream>>>(ATb, WOb, Q2, query);
  ln_kernel<<<1024, 256, 0, stream>>>(Q2, ln_g, ln_b, YLN);
  gemm_mlp1<<<dim3(64, 16), 256, 0, stream>>>(YLN, W1b, Hb, b1);
  gemm_mlp2<<<dim3(64, 8), 256, 0, stream>>>(Hb, W2b, out, b2, Q2);
}

// Round 8
// 379.623 us; speedup vs baseline: 1.5393x; 1.5393x over previous
//
#include <hip/hip_runtime.h>
#include <hip/hip_bf16.h>
#include <hip/hip_cooperative_groups.h>
#include <cmath>

namespace cg = cooperative_groups;

typedef __bf16 bf16;
typedef __attribute__((ext_vector_type(8))) __bf16 bf16x8;
typedef __attribute__((ext_vector_type(4))) __bf16 bf16x4;
typedef __attribute__((ext_vector_type(4))) float f32x4;
typedef __attribute__((ext_vector_type(4))) unsigned int u32x4;

#define LD_B 2
#define LD_L 2048
#define LD_D 512
#define HD 64
#define NTOK (LD_B * LD_L)  // 4096
#define QKV_LD 1536

// shared LDS arena: max(attn 62464, gemm 32768)
#define SMEM_BYTES 62464

__device__ __forceinline__ void gload16(const void* g, void* l) {
  __builtin_amdgcn_global_load_lds(
      (const __attribute__((address_space(1))) void*)g,
      (__attribute__((address_space(3))) void*)l, 16, 0, 0);
}

// ---- one LN row per wave (fp32 in, bf16 out) ----
__device__ __forceinline__ void ln_row(
    const float* __restrict__ x, const float* __restrict__ g,
    const float* __restrict__ b, bf16* __restrict__ out, int row, int lane)
{
  const f32x4* xr = (const f32x4*)(x + (size_t)row * LD_D);
  f32x4 v0 = xr[lane * 2], v1 = xr[lane * 2 + 1];
  float s = v0[0] + v0[1] + v0[2] + v0[3] + v1[0] + v1[1] + v1[2] + v1[3];
#pragma unroll
  for (int off = 32; off; off >>= 1) s += __shfl_xor(s, off);
  const float mu = s * (1.f / 512.f);
  float vs = 0.f;
#pragma unroll
  for (int i = 0; i < 4; ++i) {
    float a0 = v0[i] - mu; vs += a0 * a0;
    float a1 = v1[i] - mu; vs += a1 * a1;
  }
#pragma unroll
  for (int off = 32; off; off >>= 1) vs += __shfl_xor(vs, off);
  const float rstd = rsqrtf(vs * (1.f / 512.f) + 1e-5f);
  const f32x4* gr = (const f32x4*)g;
  const f32x4* br = (const f32x4*)b;
  f32x4 g0 = gr[lane * 2], g1 = gr[lane * 2 + 1];
  f32x4 b0 = br[lane * 2], b1 = br[lane * 2 + 1];
  bf16x8 o;
#pragma unroll
  for (int i = 0; i < 4; ++i) o[i] = (bf16)((v0[i] - mu) * rstd * g0[i] + b0[i]);
#pragma unroll
  for (int i = 0; i < 4; ++i) o[i + 4] = (bf16)((v1[i] - mu) * rstd * g1[i] + b1[i]);
  *(bf16x8*)(&out[(size_t)row * LD_D + lane * 8]) = o;
}

// ---- one 64x64 GEMM tile: C[row0:+64, col0:+64] = A*Bw^T (r5-proven body) ----
// EPI: 0 bf16; 1 +res f32; 2 +bias gelu bf16; 3 +bias +res f32
template <int EPI>
__device__ __forceinline__ void gemm_tile(
    const bf16* __restrict__ A, const bf16* __restrict__ Bw,
    int N, int K, bf16* __restrict__ Cb, float* __restrict__ Cf,
    const float* __restrict__ bias, const float* __restrict__ res,
    int row0, int col0, char* __restrict__ smem)
{
  const int tid = threadIdx.x;
  const int lane = tid & 63, wid = tid >> 6;
  const int wm = wid >> 1, wn = wid & 1;
  const int l15 = lane & 15, kg = lane >> 4;

  // staging chunks c0=tid, c1=256+tid; inverse-swizzled global source (rule #21)
  const int c0 = tid, c1 = 256 + tid;
  const int srow0 = c0 >> 3, scol0 = ((c0 & 7) ^ (srow0 & 7)) * 8;
  const int srow1 = c1 >> 3, scol1 = ((c1 & 7) ^ (srow1 & 7)) * 8;

  f32x4 acc[2][2];
#pragma unroll
  for (int m = 0; m < 2; ++m)
#pragma unroll
    for (int n = 0; n < 2; ++n) acc[m][n] = (f32x4){0.f, 0.f, 0.f, 0.f};

  const int nt = K >> 6;
#define STAGE(buf, k0)                                                        \
  {                                                                           \
    char* baseA = smem + (buf) * 8192;                                        \
    char* baseB = smem + 16384 + (buf) * 8192;                                \
    gload16(A + (size_t)(row0 + srow0) * K + (k0) + scol0, baseA + wid * 1024);\
    gload16(A + (size_t)(row0 + srow1) * K + (k0) + scol1, baseA + 4096 + wid * 1024);\
    gload16(Bw + (size_t)(col0 + srow0) * K + (k0) + scol0, baseB + wid * 1024);\
    gload16(Bw + (size_t)(col0 + srow1) * K + (k0) + scol1, baseB + 4096 + wid * 1024);\
  }

  STAGE(0, 0);
  __syncthreads();
  for (int t = 0; t < nt; ++t) {
    if (t + 1 < nt) STAGE((t + 1) & 1, (t + 1) << 6);
    const char* pa = smem + (t & 1) * 8192;
    const char* pb = smem + 16384 + (t & 1) * 8192;
#pragma unroll
    for (int kk = 0; kk < 2; ++kk) {
      bf16x8 af[2], bf[2];
#pragma unroll
      for (int m = 0; m < 2; ++m) {
        const int r = wm * 32 + m * 16 + l15;
        int off = r * 128 + kk * 64 + kg * 16;
        off ^= (r & 7) << 4;
        af[m] = *(const bf16x8*)(pa + off);
      }
#pragma unroll
      for (int n = 0; n < 2; ++n) {
        const int r = wn * 32 + n * 16 + l15;
        int off = r * 128 + kk * 64 + kg * 16;
        off ^= (r & 7) << 4;
        bf[n] = *(const bf16x8*)(pb + off);
      }
#pragma unroll
      for (int m = 0; m < 2; ++m)
#pragma unroll
        for (int n = 0; n < 2; ++n)
          acc[m][n] = __builtin_amdgcn_mfma_f32_16x16x32_bf16(af[m], bf[n], acc[m][n], 0, 0, 0);
    }
    __syncthreads();
  }
#undef STAGE

  const int orow = row0 + wm * 32, ocol = col0 + wn * 32;
#pragma unroll
  for (int m = 0; m < 2; ++m) {
#pragma unroll
    for (int n = 0; n < 2; ++n) {
#pragma unroll
      for (int e = 0; e < 4; ++e) {
        const int rr = orow + m * 16 + kg * 4 + e;   // C/D: row=(lane>>4)*4+reg
        const int cc = ocol + n * 16 + l15;          //      col=lane&15
        const float v = acc[m][n][e];
        const size_t oi = (size_t)rr * N + cc;
        if constexpr (EPI == 0) {
          Cb[oi] = (bf16)v;
        } else if constexpr (EPI == 1) {
          Cf[oi] = v + res[oi];
        } else if constexpr (EPI == 2) {
          float t2 = v + bias[cc];
          Cb[oi] = (bf16)(0.5f * t2 * (1.f + erff(t2 * 0.70710678118654752f)));
        } else {
          Cf[oi] = v + bias[cc] + res[oi];
        }
      }
    }
  }
}

// ---- one attention tile (64 queries of one (b,h)), r5-proven body ----
__device__ __forceinline__ void attn_tile(
    const bf16* __restrict__ QKV, bf16* __restrict__ Og,
    int qt, int bh, char* __restrict__ smem)
{
  bf16 (*Ks)[72]  = (bf16(*)[72])(smem);            // 128 rows, 18432 B
  bf16 (*Qs)[72]  = (bf16(*)[72])(smem + 18432);    // 64 rows,   9216 B
  bf16 (*Vt)[136] = (bf16(*)[136])(smem + 27648);   // 64 rows,  17408 B
  bf16 (*Ps)[136] = (bf16(*)[136])(smem + 45056);   // 64 rows,  17408 B (4 waves x16)
  const int tid = threadIdx.x;
  const int b = bh >> 3, h = bh & 7;
  const int q0 = qt * 64;
  const int j0 = q0 - 63;
  const size_t baseQ = (size_t)b * LD_L * QKV_LD + h * HD;
  const size_t baseK = baseQ + 512;
  const size_t baseV = baseQ + 1024;
  const size_t baseO = (size_t)b * LD_L * LD_D + h * HD;

  __syncthreads();  // LDS arena handoff
  for (int c = tid; c < 128 * 8; c += 256) {
    const int r = c >> 3, d0 = (c & 7) * 8;
    const int j = j0 + r;
    u32x4 kv = (u32x4){0u, 0u, 0u, 0u};
    bf16x8 vv = (bf16x8)(__bf16)0.f;
    if (j >= 0 && j < LD_L) {
      kv = *(const u32x4*)(QKV + baseK + (size_t)j * QKV_LD + d0);
      vv = *(const bf16x8*)(QKV + baseV + (size_t)j * QKV_LD + d0);
    }
    *(u32x4*)(&Ks[r][d0]) = kv;
#pragma unroll
    for (int dd = 0; dd < 8; ++dd) Vt[d0 + dd][r] = vv[dd];
  }
  for (int c = tid; c < 64 * 8; c += 256) {
    const int r = c >> 3, d0 = (c & 7) * 8;
    *(u32x4*)(&Qs[r][d0]) =
        *(const u32x4*)(QKV + baseQ + (size_t)(q0 + r) * QKV_LD + d0);
  }
  __syncthreads();

  const int lane = tid & 63, wid = tid >> 6;
  const int l15 = lane & 15, kg = lane >> 4;
  const int klo = 63 - q0;

  bf16x8 qf[2];
#pragma unroll
  for (int kk = 0; kk < 2; ++kk)
    qf[kk] = *(const bf16x8*)(&Qs[wid * 16 + l15][kk * 32 + kg * 8]);
  f32x4 s[8];
#pragma unroll
  for (int n = 0; n < 8; ++n) s[n] = (f32x4){0.f, 0.f, 0.f, 0.f};
#pragma unroll
  for (int kk = 0; kk < 2; ++kk)
#pragma unroll
    for (int n = 0; n < 8; ++n) {
      bf16x8 kf = *(const bf16x8*)(&Ks[n * 16 + l15][kk * 32 + kg * 8]);
      s[n] = __builtin_amdgcn_mfma_f32_16x16x32_bf16(qf[kk], kf, s[n], 0, 0, 0);
    }

  float p[8][4];
  float mx[4], sm[4];
#pragma unroll
  for (int e = 0; e < 4; ++e) { mx[e] = -INFINITY; sm[e] = 0.f; }
#pragma unroll
  for (int n = 0; n < 8; ++n) {
    const int k = n * 16 + l15;
#pragma unroll
    for (int e = 0; e < 4; ++e) {
      const int qi = wid * 16 + kg * 4 + e;
      const bool ok = (k >= qi) & (k <= qi + 63) & (k >= klo);
      float sv = ok ? s[n][e] * 0.125f : -INFINITY;
      p[n][e] = sv;
      mx[e] = fmaxf(mx[e], sv);
    }
  }
#pragma unroll
  for (int off = 8; off; off >>= 1)
#pragma unroll
    for (int e = 0; e < 4; ++e) mx[e] = fmaxf(mx[e], __shfl_xor(mx[e], off));
#pragma unroll
  for (int n = 0; n < 8; ++n)
#pragma unroll
    for (int e = 0; e < 4; ++e) {
      float pv = (p[n][e] == -INFINITY) ? 0.f : __expf(p[n][e] - mx[e]);
      p[n][e] = pv;
      sm[e] += pv;
    }
#pragma unroll
  for (int off = 8; off; off >>= 1)
#pragma unroll
    for (int e = 0; e < 4; ++e) sm[e] += __shfl_xor(sm[e], off);
  float rs[4];
#pragma unroll
  for (int e = 0; e < 4; ++e) rs[e] = 1.f / sm[e];

#pragma unroll
  for (int n = 0; n < 8; ++n)
#pragma unroll
    for (int e = 0; e < 4; ++e)
      Ps[wid * 16 + kg * 4 + e][n * 16 + l15] = (bf16)(p[n][e] * rs[e]);

  f32x4 o[4];
#pragma unroll
  for (int n = 0; n < 4; ++n) o[n] = (f32x4){0.f, 0.f, 0.f, 0.f};
#pragma unroll
  for (int ks = 0; ks < 4; ++ks) {
    bf16x8 pf = *(const bf16x8*)(&Ps[wid * 16 + l15][ks * 32 + kg * 8]);
#pragma unroll
    for (int n = 0; n < 4; ++n) {
      bf16x8 vf = *(const bf16x8*)(&Vt[n * 16 + l15][ks * 32 + kg * 8]);
      o[n] = __builtin_amdgcn_mfma_f32_16x16x32_bf16(pf, vf, o[n], 0, 0, 0);
    }
  }

  const int q = q0 + wid * 16 + kg * 4;
#pragma unroll
  for (int n = 0; n < 4; ++n)
#pragma unroll
    for (int e = 0; e < 4; ++e)
      Og[baseO + (size_t)(q + e) * LD_D + n * 16 + l15] = (bf16)o[n][e];
}

// ---- persistent cooperative kernel: whole transformer block, 7 stages ----
__global__ __launch_bounds__(256, 2) void fused_block_kernel(
    const float* __restrict__ query, const float* __restrict__ ln_g,
    const float* __restrict__ ln_b,
    const float* __restrict__ wq, const float* __restrict__ wk,
    const float* __restrict__ wv, const float* __restrict__ wo,
    const float* __restrict__ w1, const float* __restrict__ b1,
    const float* __restrict__ w2, const float* __restrict__ b2,
    float* __restrict__ out,
    bf16* __restrict__ WQKVb, bf16* __restrict__ WOb,
    bf16* __restrict__ W1b, bf16* __restrict__ W2b,
    bf16* __restrict__ XLN, bf16* __restrict__ QKVb,
    bf16* __restrict__ ATb, float* __restrict__ Q2,
    bf16* __restrict__ YLN, bf16* __restrict__ Hb)
{
  __shared__ __align__(16) char smem[SMEM_BYTES];
  cg::grid_group grid = cg::this_grid();
  const int tid = threadIdx.x;
  const int wi = blockIdx.x;
  const int G = gridDim.x;
  const int lane = tid & 63, wid = tid >> 6;

  // stage 0: weight cast + LN1
  for (int idx = wi * 256 + tid; idx < 524288; idx += G * 256) {
    const float* src; bf16* dst; int off;
    if (idx < 262144) {
      int seg = idx >> 16; off = idx & 65535;
      src = seg == 0 ? wq : seg == 1 ? wk : seg == 2 ? wv : wo;
      dst = seg == 0 ? WQKVb : seg == 1 ? (WQKVb + 262144)
          : seg == 2 ? (WQKVb + 524288) : WOb;
    } else {
      int t = idx - 262144;
      int seg = t >> 17; off = t & 131071;
      src = seg ? w2 : w1;
      dst = seg ? W2b : W1b;
    }
    f32x4 v = ((const f32x4*)src)[off];
    bf16x4 o;
    o[0] = (bf16)v[0]; o[1] = (bf16)v[1]; o[2] = (bf16)v[2]; o[3] = (bf16)v[3];
    ((bf16x4*)dst)[off] = o;
  }
  for (int row = wi * 4 + wid; row < NTOK; row += G * 4)
    ln_row(query, ln_g, ln_b, XLN, row, lane);
  grid.sync();

  // stage 1: fused QKV GEMM (64x64 tiles, 64 row-tiles x 24 col-tiles)
  for (int t = wi; t < 1536; t += G)
    gemm_tile<0>(XLN, WQKVb, QKV_LD, 512, QKVb, nullptr, nullptr, nullptr,
                 (t & 63) << 6, (t >> 6) << 6, smem);
  grid.sync();

  // stage 2: sliding-window attention (512 items)
  for (int it = wi; it < 512; it += G)
    attn_tile(QKVb, ATb, it & 31, it >> 5, smem);
  grid.sync();

  // stage 3: O-proj + residual (f32)
  for (int t = wi; t < 512; t += G)
    gemm_tile<1>(ATb, WOb, 512, 512, nullptr, Q2, nullptr, query,
                 (t & 63) << 6, (t >> 6) << 6, smem);
  grid.sync();

  // stage 4: LN2
  for (int row = wi * 4 + wid; row < NTOK; row += G * 4)
    ln_row(Q2, ln_g, ln_b, YLN, row, lane);
  grid.sync();

  // stage 5: MLP1 + bias + gelu (64 x 16 tiles)
  for (int t = wi; t < 1024; t += G)
    gemm_tile<2>(YLN, W1b, 1024, 512, Hb, nullptr, b1, nullptr,
                 (t & 63) << 6, (t >> 6) << 6, smem);
  grid.sync();

  // stage 6: MLP2 + bias + residual -> out
  for (int t = wi; t < 512; t += G)
    gemm_tile<3>(Hb, W2b, 512, 1024, nullptr, out, b2, Q2,
                 (t & 63) << 6, (t >> 6) << 6, smem);
}

// ---------------- launch ----------------
extern "C" void kernel_launch(void* const* d_in, const int* in_sizes, int n_in,
                              void* d_out, int out_size, void* d_ws, size_t ws_size,
                              hipStream_t stream)
{
  const float* query = (const float*)d_in[0];
  const float* ln_g = (const float*)d_in[1];
  const float* ln_b = (const float*)d_in[2];
  const float* wq = (const float*)d_in[3];
  const float* wk = (const float*)d_in[4];
  const float* wv = (const float*)d_in[5];
  const float* wo = (const float*)d_in[6];
  const float* w1 = (const float*)d_in[7];
  const float* b1 = (const float*)d_in[8];
  const float* w2 = (const float*)d_in[9];
  const float* b2 = (const float*)d_in[10];
  float* out = (float*)d_out;

  char* ws = (char*)d_ws;
  bf16* WQKVb = (bf16*)(ws + 0x000000);  // [1536][512] = 1.5MB
  bf16* WOb = (bf16*)(ws + 0x180000);    // 512KB
  bf16* W1b = (bf16*)(ws + 0x200000);    // 1MB
  bf16* W2b = (bf16*)(ws + 0x300000);    // 1MB
  bf16* XLN = (bf16*)(ws + 0x400000);    // 4MB
  bf16* QKVb = (bf16*)(ws + 0x800000);   // [4096][1536] = 12MB
  bf16* ATb = (bf16*)(ws + 0x1400000);   // 4MB
  float* Q2 = (float*)(ws + 0x1800000);  // 8MB
  bf16* YLN = (bf16*)(ws + 0x2000000);   // 4MB
  bf16* Hb = (bf16*)(ws + 0x2400000);    // 8MB (end 44MB)

  int nb = 0;
  if (hipOccupancyMaxActiveBlocksPerMultiprocessor(&nb, fused_block_kernel, 256, 0)
          != hipSuccess || nb < 1)
    nb = 1;
  int grid = nb * 256;
  if (grid > 512) grid = 512;

  void* args[] = {
      (void*)&query, (void*)&ln_g, (void*)&ln_b,
      (void*)&wq, (void*)&wk, (void*)&wv, (void*)&wo,
      (void*)&w1, (void*)&b1, (void*)&w2, (void*)&b2,
      (void*)&out,
      (void*)&WQKVb, (void*)&WOb, (void*)&W1b, (void*)&W2b,
      (void*)&XLN, (void*)&QKVb, (void*)&ATb, (void*)&Q2,
      (void*)&YLN, (void*)&Hb};
  hipLaunchCooperativeKernel((void*)fused_block_kernel, dim3(grid), dim3(256),
                             args, 0, stream);
}

// Round 9
// 166.341 us; speedup vs baseline: 3.5130x; 2.2822x over previous
//
#include <hip/hip_runtime.h>
#include <hip/hip_bf16.h>
#include <cmath>

typedef __bf16 bf16;
typedef __attribute__((ext_vector_type(8))) __bf16 bf16x8;
typedef __attribute__((ext_vector_type(4))) __bf16 bf16x4;
typedef __attribute__((ext_vector_type(4))) float f32x4;
typedef __attribute__((ext_vector_type(4))) unsigned int u32x4;

#define LD_B 2
#define LD_L 2048
#define LD_D 512
#define HD 64
#define NTOK (LD_B * LD_L)  // 4096
#define QKV_LD 1536

__device__ __forceinline__ void gload16(const void* g, void* l) {
  __builtin_amdgcn_global_load_lds(
      (const __attribute__((address_space(1))) void*)g,
      (__attribute__((address_space(3))) void*)l, 16, 0, 0);
}

// ---- prep: weight cast + LN1, grid-stride over both work sets (512 blocks) --
__global__ __launch_bounds__(256) void prep_kernel(
    const float* __restrict__ x, const float* __restrict__ g,
    const float* __restrict__ b, bf16* __restrict__ xln,
    const float* __restrict__ s0, const float* __restrict__ s1,
    const float* __restrict__ s2, const float* __restrict__ s3,
    const float* __restrict__ s4, const float* __restrict__ s5,
    bf16* __restrict__ d0, bf16* __restrict__ d1, bf16* __restrict__ d2,
    bf16* __restrict__ d3, bf16* __restrict__ d4, bf16* __restrict__ d5)
{
  const int tid = threadIdx.x;
  const int G = gridDim.x;
  // cast: 524288 f32x4 chunks
  for (int idx = blockIdx.x * 256 + tid; idx < 524288; idx += G * 256) {
    const float* src; bf16* dst; int off;
    if (idx < 262144) {
      int seg = idx >> 16; off = idx & 65535;
      src = seg == 0 ? s0 : seg == 1 ? s1 : seg == 2 ? s2 : s3;
      dst = seg == 0 ? d0 : seg == 1 ? d1 : seg == 2 ? d2 : d3;
    } else {
      int t = idx - 262144;
      int seg = t >> 17; off = t & 131071;
      src = seg ? s5 : s4;
      dst = seg ? d5 : d4;
    }
    f32x4 v = ((const f32x4*)src)[off];
    bf16x4 o;
    o[0] = (bf16)v[0]; o[1] = (bf16)v[1]; o[2] = (bf16)v[2]; o[3] = (bf16)v[3];
    ((bf16x4*)dst)[off] = o;
  }
  // LN1: one row per wave
  const int wid = tid >> 6, lane = tid & 63;
  for (int row = blockIdx.x * 4 + wid; row < NTOK; row += G * 4) {
    const f32x4* xr = (const f32x4*)(x + (size_t)row * LD_D);
    f32x4 v0 = xr[lane * 2], v1 = xr[lane * 2 + 1];
    float s = v0[0] + v0[1] + v0[2] + v0[3] + v1[0] + v1[1] + v1[2] + v1[3];
#pragma unroll
    for (int off = 32; off; off >>= 1) s += __shfl_xor(s, off);
    const float mu = s * (1.f / 512.f);
    float vs = 0.f;
#pragma unroll
    for (int i = 0; i < 4; ++i) {
      float a0 = v0[i] - mu; vs += a0 * a0;
      float a1 = v1[i] - mu; vs += a1 * a1;
    }
#pragma unroll
    for (int off = 32; off; off >>= 1) vs += __shfl_xor(vs, off);
    const float rstd = rsqrtf(vs * (1.f / 512.f) + 1e-5f);
    const f32x4* gr = (const f32x4*)g;
    const f32x4* br = (const f32x4*)b;
    f32x4 g0 = gr[lane * 2], g1 = gr[lane * 2 + 1];
    f32x4 b0 = br[lane * 2], b1 = br[lane * 2 + 1];
    bf16x8 o;
#pragma unroll
    for (int i = 0; i < 4; ++i) o[i] = (bf16)((v0[i] - mu) * rstd * g0[i] + b0[i]);
#pragma unroll
    for (int i = 0; i < 4; ++i) o[i + 4] = (bf16)((v1[i] - mu) * rstd * g1[i] + b1[i]);
    *(bf16x8*)(&xln[(size_t)row * LD_D + lane * 8]) = o;
  }
}

// ---- LN2, grid-stride (512 blocks) ----
__global__ __launch_bounds__(256) void ln_kernel(
    const float* __restrict__ x, const float* __restrict__ g,
    const float* __restrict__ b, bf16* __restrict__ out)
{
  const int wid = threadIdx.x >> 6, lane = threadIdx.x & 63;
  for (int row = blockIdx.x * 4 + wid; row < NTOK; row += gridDim.x * 4) {
    const f32x4* xr = (const f32x4*)(x + (size_t)row * LD_D);
    f32x4 v0 = xr[lane * 2], v1 = xr[lane * 2 + 1];
    float s = v0[0] + v0[1] + v0[2] + v0[3] + v1[0] + v1[1] + v1[2] + v1[3];
#pragma unroll
    for (int off = 32; off; off >>= 1) s += __shfl_xor(s, off);
    const float mu = s * (1.f / 512.f);
    float vs = 0.f;
#pragma unroll
    for (int i = 0; i < 4; ++i) {
      float a0 = v0[i] - mu; vs += a0 * a0;
      float a1 = v1[i] - mu; vs += a1 * a1;
    }
#pragma unroll
    for (int off = 32; off; off >>= 1) vs += __shfl_xor(vs, off);
    const float rstd = rsqrtf(vs * (1.f / 512.f) + 1e-5f);
    const f32x4* gr = (const f32x4*)g;
    const f32x4* br = (const f32x4*)b;
    f32x4 g0 = gr[lane * 2], g1 = gr[lane * 2 + 1];
    f32x4 b0 = br[lane * 2], b1 = br[lane * 2 + 1];
    bf16x8 o;
#pragma unroll
    for (int i = 0; i < 4; ++i) o[i] = (bf16)((v0[i] - mu) * rstd * g0[i] + b0[i]);
#pragma unroll
    for (int i = 0; i < 4; ++i) o[i + 4] = (bf16)((v1[i] - mu) * rstd * g1[i] + b1[i]);
    *(bf16x8*)(&out[(size_t)row * LD_D + lane * 8]) = o;
  }
}

// ---- GEMM: grid-stride over 64x64 tiles (r5-proven tile body) ----
// tile t: row0 = (t & 63)*64 (64 row-tiles, M=4096), col0 = (t >> 6)*64.
// EPI: 0 bf16; 1 +res f32; 2 +bias gelu bf16; 3 +bias +res f32
template <int COLT, int EPI>
__device__ __forceinline__ void gemm_gs(
    const bf16* __restrict__ A, const bf16* __restrict__ Bw,
    int N, int K, bf16* __restrict__ Cb, float* __restrict__ Cf,
    const float* __restrict__ bias, const float* __restrict__ res)
{
  __shared__ bf16 As[2][4096];
  __shared__ bf16 Bs[2][4096];
  const int tid = threadIdx.x;
  const int lane = tid & 63, wid = tid >> 6;
  const int wm = wid >> 1, wn = wid & 1;
  const int l15 = lane & 15, kg = lane >> 4;

  // staging chunks (loop-invariant): inverse-swizzled source (rule #21)
  int srow[2], scol[2];
#pragma unroll
  for (int i = 0; i < 2; ++i) {
    int c = i * 256 + tid;
    srow[i] = c >> 3;
    scol[i] = ((c & 7) ^ (srow[i] & 7)) * 8;
  }
  const int nt = K >> 6;

  for (int t = blockIdx.x; t < 64 * COLT; t += gridDim.x) {
    const int row0 = (t & 63) << 6, col0 = (t >> 6) << 6;

    f32x4 acc[2][2];
#pragma unroll
    for (int m = 0; m < 2; ++m)
#pragma unroll
      for (int n = 0; n < 2; ++n) acc[m][n] = (f32x4){0.f, 0.f, 0.f, 0.f};

#define STAGE(buf, k0)                                                      \
  {                                                                         \
    _Pragma("unroll")                                                       \
    for (int i = 0; i < 2; ++i) {                                           \
      const bf16* ga = A + (size_t)(row0 + srow[i]) * K + (k0) + scol[i];   \
      const bf16* gb = Bw + (size_t)(col0 + srow[i]) * K + (k0) + scol[i];  \
      char* la = (char*)&As[buf][0] + (i * 4 + wid) * 1024;                 \
      char* lb = (char*)&Bs[buf][0] + (i * 4 + wid) * 1024;                 \
      gload16(ga, la);                                                      \
      gload16(gb, lb);                                                      \
    }                                                                       \
  }

    STAGE(0, 0);
    __syncthreads();
    for (int tt = 0; tt < nt; ++tt) {
      if (tt + 1 < nt) STAGE((tt + 1) & 1, (tt + 1) << 6);
      const char* pa = (const char*)&As[tt & 1][0];
      const char* pb = (const char*)&Bs[tt & 1][0];
#pragma unroll
      for (int kk = 0; kk < 2; ++kk) {
        bf16x8 af[2], bf[2];
#pragma unroll
        for (int m = 0; m < 2; ++m) {
          const int r = wm * 32 + m * 16 + l15;
          int off = r * 128 + kk * 64 + kg * 16;
          off ^= (r & 7) << 4;
          af[m] = *(const bf16x8*)(pa + off);
        }
#pragma unroll
        for (int n = 0; n < 2; ++n) {
          const int r = wn * 32 + n * 16 + l15;
          int off = r * 128 + kk * 64 + kg * 16;
          off ^= (r & 7) << 4;
          bf[n] = *(const bf16x8*)(pb + off);
        }
#pragma unroll
        for (int m = 0; m < 2; ++m)
#pragma unroll
          for (int n = 0; n < 2; ++n)
            acc[m][n] = __builtin_amdgcn_mfma_f32_16x16x32_bf16(af[m], bf[n], acc[m][n], 0, 0, 0);
      }
      __syncthreads();
    }
#undef STAGE

    const int orow = row0 + wm * 32, ocol = col0 + wn * 32;
#pragma unroll
    for (int m = 0; m < 2; ++m) {
#pragma unroll
      for (int n = 0; n < 2; ++n) {
#pragma unroll
        for (int e = 0; e < 4; ++e) {
          const int rr = orow + m * 16 + kg * 4 + e;   // C/D row=(lane>>4)*4+reg
          const int cc = ocol + n * 16 + l15;          //     col=lane&15
          const float v = acc[m][n][e];
          const size_t oi = (size_t)rr * N + cc;
          if constexpr (EPI == 0) {
            Cb[oi] = (bf16)v;
          } else if constexpr (EPI == 1) {
            Cf[oi] = v + res[oi];
          } else if constexpr (EPI == 2) {
            float t2 = v + bias[cc];
            Cb[oi] = (bf16)(0.5f * t2 * (1.f + erff(t2 * 0.70710678118654752f)));
          } else {
            Cf[oi] = v + bias[cc] + res[oi];
          }
        }
      }
    }
  }
}

__global__ __launch_bounds__(256) void gemm_qkv(
    const bf16* __restrict__ A, const bf16* __restrict__ Bw,
    bf16* __restrict__ Cb)
{
  gemm_gs<24, 0>(A, Bw, QKV_LD, 512, Cb, nullptr, nullptr, nullptr);
}
__global__ __launch_bounds__(256) void gemm_oproj(
    const bf16* __restrict__ A, const bf16* __restrict__ Bw,
    float* __restrict__ Cf, const float* __restrict__ res)
{
  gemm_gs<8, 1>(A, Bw, 512, 512, nullptr, Cf, nullptr, res);
}
__global__ __launch_bounds__(256) void gemm_mlp1(
    const bf16* __restrict__ A, const bf16* __restrict__ Bw,
    bf16* __restrict__ Cb, const float* __restrict__ bias)
{
  gemm_gs<16, 2>(A, Bw, 1024, 512, Cb, nullptr, bias, nullptr);
}
__global__ __launch_bounds__(256) void gemm_mlp2(
    const bf16* __restrict__ A, const bf16* __restrict__ Bw,
    float* __restrict__ Cf, const float* __restrict__ bias,
    const float* __restrict__ res)
{
  gemm_gs<8, 3>(A, Bw, 512, 1024, nullptr, Cf, bias, res);
}

// ---- sliding-window causal attention (r5-proven, 512 wgs already) ----
__global__ __launch_bounds__(256) void attn_kernel(
    const bf16* __restrict__ QKV, bf16* __restrict__ Og)
{
  constexpr int STK = 72;
  constexpr int STP = 136;
  __shared__ bf16 Ks[128][STK];
  __shared__ bf16 Qs[64][STK];
  __shared__ bf16 Vt[64][STP];
  __shared__ bf16 Ps[4][16][STP];
  const int tid = threadIdx.x;
  const int qt = blockIdx.x, bh = blockIdx.y;
  const int b = bh >> 3, h = bh & 7;
  const int q0 = qt * 64;
  const int j0 = q0 - 63;
  const size_t baseQ = (size_t)b * LD_L * QKV_LD + h * HD;
  const size_t baseK = baseQ + 512;
  const size_t baseV = baseQ + 1024;
  const size_t baseO = (size_t)b * LD_L * LD_D + h * HD;

  for (int c = tid; c < 128 * 8; c += 256) {
    const int r = c >> 3, d0 = (c & 7) * 8;
    const int j = j0 + r;
    u32x4 kv = (u32x4){0u, 0u, 0u, 0u};
    bf16x8 vv = (bf16x8)(__bf16)0.f;
    if (j >= 0 && j < LD_L) {
      kv = *(const u32x4*)(QKV + baseK + (size_t)j * QKV_LD + d0);
      vv = *(const bf16x8*)(QKV + baseV + (size_t)j * QKV_LD + d0);
    }
    *(u32x4*)(&Ks[r][d0]) = kv;
#pragma unroll
    for (int dd = 0; dd < 8; ++dd) Vt[d0 + dd][r] = vv[dd];
  }
  for (int c = tid; c < 64 * 8; c += 256) {
    const int r = c >> 3, d0 = (c & 7) * 8;
    *(u32x4*)(&Qs[r][d0]) =
        *(const u32x4*)(QKV + baseQ + (size_t)(q0 + r) * QKV_LD + d0);
  }
  __syncthreads();

  const int lane = tid & 63, wid = tid >> 6;
  const int l15 = lane & 15, kg = lane >> 4;
  const int klo = 63 - q0;

  bf16x8 qf[2];
#pragma unroll
  for (int kk = 0; kk < 2; ++kk)
    qf[kk] = *(const bf16x8*)(&Qs[wid * 16 + l15][kk * 32 + kg * 8]);
  f32x4 s[8];
#pragma unroll
  for (int n = 0; n < 8; ++n) s[n] = (f32x4){0.f, 0.f, 0.f, 0.f};
#pragma unroll
  for (int kk = 0; kk < 2; ++kk)
#pragma unroll
    for (int n = 0; n < 8; ++n) {
      bf16x8 kf = *(const bf16x8*)(&Ks[n * 16 + l15][kk * 32 + kg * 8]);
      s[n] = __builtin_amdgcn_mfma_f32_16x16x32_bf16(qf[kk], kf, s[n], 0, 0, 0);
    }

  float p[8][4];
  float mx[4], sm[4];
#pragma unroll
  for (int e = 0; e < 4; ++e) { mx[e] = -INFINITY; sm[e] = 0.f; }
#pragma unroll
  for (int n = 0; n < 8; ++n) {
    const int k = n * 16 + l15;
#pragma unroll
    for (int e = 0; e < 4; ++e) {
      const int qi = wid * 16 + kg * 4 + e;
      const bool ok = (k >= qi) & (k <= qi + 63) & (k >= klo);
      float sv = ok ? s[n][e] * 0.125f : -INFINITY;
      p[n][e] = sv;
      mx[e] = fmaxf(mx[e], sv);
    }
  }
#pragma unroll
  for (int off = 8; off; off >>= 1)
#pragma unroll
    for (int e = 0; e < 4; ++e) mx[e] = fmaxf(mx[e], __shfl_xor(mx[e], off));
#pragma unroll
  for (int n = 0; n < 8; ++n)
#pragma unroll
    for (int e = 0; e < 4; ++e) {
      float pv = (p[n][e] == -INFINITY) ? 0.f : __expf(p[n][e] - mx[e]);
      p[n][e] = pv;
      sm[e] += pv;
    }
#pragma unroll
  for (int off = 8; off; off >>= 1)
#pragma unroll
    for (int e = 0; e < 4; ++e) sm[e] += __shfl_xor(sm[e], off);
  float rs[4];
#pragma unroll
  for (int e = 0; e < 4; ++e) rs[e] = 1.f / sm[e];

#pragma unroll
  for (int n = 0; n < 8; ++n)
#pragma unroll
    for (int e = 0; e < 4; ++e)
      Ps[wid][kg * 4 + e][n * 16 + l15] = (bf16)(p[n][e] * rs[e]);

  f32x4 o[4];
#pragma unroll
  for (int n = 0; n < 4; ++n) o[n] = (f32x4){0.f, 0.f, 0.f, 0.f};
#pragma unroll
  for (int ks = 0; ks < 4; ++ks) {
    bf16x8 pf = *(const bf16x8*)(&Ps[wid][l15][ks * 32 + kg * 8]);
#pragma unroll
    for (int n = 0; n < 4; ++n) {
      bf16x8 vf = *(const bf16x8*)(&Vt[n * 16 + l15][ks * 32 + kg * 8]);
      o[n] = __builtin_amdgcn_mfma_f32_16x16x32_bf16(pf, vf, o[n], 0, 0, 0);
    }
  }

  const int q = q0 + wid * 16 + kg * 4;
#pragma unroll
  for (int n = 0; n < 4; ++n)
#pragma unroll
    for (int e = 0; e < 4; ++e)
      Og[baseO + (size_t)(q + e) * LD_D + n * 16 + l15] = (bf16)o[n][e];
}

// ---------------- launch ----------------
extern "C" void kernel_launch(void* const* d_in, const int* in_sizes, int n_in,
                              void* d_out, int out_size, void* d_ws, size_t ws_size,
                              hipStream_t stream)
{
  const float* query = (const float*)d_in[0];
  const float* ln_g = (const float*)d_in[1];
  const float* ln_b = (const float*)d_in[2];
  const float* wq = (const float*)d_in[3];
  const float* wk = (const float*)d_in[4];
  const float* wv = (const float*)d_in[5];
  const float* wo = (const float*)d_in[6];
  const float* w1 = (const float*)d_in[7];
  const float* b1 = (const float*)d_in[8];
  const float* w2 = (const float*)d_in[9];
  const float* b2 = (const float*)d_in[10];
  float* out = (float*)d_out;

  char* ws = (char*)d_ws;
  bf16* WQKVb = (bf16*)(ws + 0x000000);  // [1536][512] = 1.5MB
  bf16* WOb = (bf16*)(ws + 0x180000);    // 512KB
  bf16* W1b = (bf16*)(ws + 0x200000);    // 1MB
  bf16* W2b = (bf16*)(ws + 0x300000);    // 1MB
  bf16* XLN = (bf16*)(ws + 0x400000);    // 4MB
  bf16* QKVb = (bf16*)(ws + 0x800000);   // [4096][1536] = 12MB
  bf16* ATb = (bf16*)(ws + 0x1400000);   // 4MB
  float* Q2 = (float*)(ws + 0x1800000);  // 8MB
  bf16* YLN = (bf16*)(ws + 0x2000000);   // 4MB
  bf16* Hb = (bf16*)(ws + 0x2400000);    // 8MB (end 44MB)

  prep_kernel<<<512, 256, 0, stream>>>(
      query, ln_g, ln_b, XLN,
      wq, wk, wv, wo, w1, w2,
      WQKVb, WQKVb + 262144, WQKVb + 524288, WOb, W1b, W2b);
  gemm_qkv<<<512, 256, 0, stream>>>(XLN, WQKVb, QKVb);
  attn_kernel<<<dim3(32, 16), 256, 0, stream>>>(QKVb, ATb);
  gemm_oproj<<<512, 256, 0, stream>>>(ATb, WOb, Q2, query);
  ln_kernel<<<512, 256, 0, stream>>>(Q2, ln_g, ln_b, YLN);
  gemm_mlp1<<<512, 256, 0, stream>>>(YLN, W1b, Hb, b1);
  gemm_mlp2<<<512, 256, 0, stream>>>(Hb, W2b, out, b2, Q2);
}

// Round 10
// 153.222 us; speedup vs baseline: 3.8138x; 1.0856x over previous
//
#include <hip/hip_runtime.h>
#include <hip/hip_bf16.h>
#include <cmath>

typedef __bf16 bf16;
typedef __attribute__((ext_vector_type(8))) __bf16 bf16x8;
typedef __attribute__((ext_vector_type(4))) __bf16 bf16x4;
typedef __attribute__((ext_vector_type(4))) float f32x4;
typedef __attribute__((ext_vector_type(4))) unsigned int u32x4;

#define LD_B 2
#define LD_L 2048
#define LD_D 512
#define HD 64
#define NTOK (LD_B * LD_L)  // 4096
#define QKV_LD 1536

__device__ __forceinline__ void gload16(const void* g, void* l) {
  __builtin_amdgcn_global_load_lds(
      (const __attribute__((address_space(1))) void*)g,
      (__attribute__((address_space(3))) void*)l, 16, 0, 0);
}

// ------------- prep: LN1 (blocks 0..1023) + weight cast (blocks 1024..3071) --
__global__ __launch_bounds__(256) void prep_kernel(
    const float* __restrict__ x, const float* __restrict__ g,
    const float* __restrict__ b, bf16* __restrict__ xln,
    const float* __restrict__ s0, const float* __restrict__ s1,
    const float* __restrict__ s2, const float* __restrict__ s3,
    const float* __restrict__ s4, const float* __restrict__ s5,
    bf16* __restrict__ d0, bf16* __restrict__ d1, bf16* __restrict__ d2,
    bf16* __restrict__ d3, bf16* __restrict__ d4, bf16* __restrict__ d5)
{
  if (blockIdx.x >= 1024) {
    int idx = (blockIdx.x - 1024) * 256 + threadIdx.x;  // 0..524287
    const float* src; bf16* dst; int off;
    if (idx < 262144) {
      int seg = idx >> 16; off = idx & 65535;
      src = seg == 0 ? s0 : seg == 1 ? s1 : seg == 2 ? s2 : s3;
      dst = seg == 0 ? d0 : seg == 1 ? d1 : seg == 2 ? d2 : d3;
    } else {
      int t = idx - 262144;
      int seg = t >> 17; off = t & 131071;
      src = seg ? s5 : s4;
      dst = seg ? d5 : d4;
    }
    f32x4 v = ((const f32x4*)src)[off];
    bf16x4 o;
    o[0] = (bf16)v[0]; o[1] = (bf16)v[1]; o[2] = (bf16)v[2]; o[3] = (bf16)v[3];
    ((bf16x4*)dst)[off] = o;
    return;
  }
  const int wid = threadIdx.x >> 6, lane = threadIdx.x & 63;
  const int row = blockIdx.x * 4 + wid;
  const f32x4* xr = (const f32x4*)(x + (size_t)row * LD_D);
  f32x4 v0 = xr[lane * 2], v1 = xr[lane * 2 + 1];
  float s = v0[0] + v0[1] + v0[2] + v0[3] + v1[0] + v1[1] + v1[2] + v1[3];
#pragma unroll
  for (int off = 32; off; off >>= 1) s += __shfl_xor(s, off);
  const float mu = s * (1.f / 512.f);
  float vs = 0.f;
#pragma unroll
  for (int i = 0; i < 4; ++i) {
    float a0 = v0[i] - mu; vs += a0 * a0;
    float a1 = v1[i] - mu; vs += a1 * a1;
  }
#pragma unroll
  for (int off = 32; off; off >>= 1) vs += __shfl_xor(vs, off);
  const float rstd = rsqrtf(vs * (1.f / 512.f) + 1e-5f);
  const f32x4* gr = (const f32x4*)g;
  const f32x4* br = (const f32x4*)b;
  f32x4 g0 = gr[lane * 2], g1 = gr[lane * 2 + 1];
  f32x4 b0 = br[lane * 2], b1 = br[lane * 2 + 1];
  bf16x8 o;
#pragma unroll
  for (int i = 0; i < 4; ++i) o[i] = (bf16)((v0[i] - mu) * rstd * g0[i] + b0[i]);
#pragma unroll
  for (int i = 0; i < 4; ++i) o[i + 4] = (bf16)((v1[i] - mu) * rstd * g1[i] + b1[i]);
  *(bf16x8*)(&xln[(size_t)row * LD_D + lane * 8]) = o;
}

// ---------------- layernorm (fp32 in, bf16 out), one wave per 512-row -------
__global__ __launch_bounds__(256) void ln_kernel(
    const float* __restrict__ x, const float* __restrict__ g,
    const float* __restrict__ b, bf16* __restrict__ out)
{
  const int wid = threadIdx.x >> 6, lane = threadIdx.x & 63;
  const int row = blockIdx.x * 4 + wid;
  const f32x4* xr = (const f32x4*)(x + (size_t)row * LD_D);
  f32x4 v0 = xr[lane * 2], v1 = xr[lane * 2 + 1];
  float s = v0[0] + v0[1] + v0[2] + v0[3] + v1[0] + v1[1] + v1[2] + v1[3];
#pragma unroll
  for (int off = 32; off; off >>= 1) s += __shfl_xor(s, off);
  const float mu = s * (1.f / 512.f);
  float vs = 0.f;
#pragma unroll
  for (int i = 0; i < 4; ++i) {
    float a0 = v0[i] - mu; vs += a0 * a0;
    float a1 = v1[i] - mu; vs += a1 * a1;
  }
#pragma unroll
  for (int off = 32; off; off >>= 1) vs += __shfl_xor(vs, off);
  const float rstd = rsqrtf(vs * (1.f / 512.f) + 1e-5f);
  const f32x4* gr = (const f32x4*)g;
  const f32x4* br = (const f32x4*)b;
  f32x4 g0 = gr[lane * 2], g1 = gr[lane * 2 + 1];
  f32x4 b0 = br[lane * 2], b1 = br[lane * 2 + 1];
  bf16x8 o;
#pragma unroll
  for (int i = 0; i < 4; ++i) o[i] = (bf16)((v0[i] - mu) * rstd * g0[i] + b0[i]);
#pragma unroll
  for (int i = 0; i < 4; ++i) o[i + 4] = (bf16)((v1[i] - mu) * rstd * g1[i] + b1[i]);
  *(bf16x8*)(&out[(size_t)row * LD_D + lane * 8]) = o;
}

// ---------------- GEMM: C[M,N] = A[M,K] * Bw[N,K]^T, bf16 in, fp32 acc ------
// 64x64 tile, BK=32, 3-buffer LDS ring, depth-2 prefetch, counted vmcnt
// (never drain the newest stage at a barrier). 4 waves (2x2), wave 32x32.
// LDS [64][32] bf16 linear per buffer; swizzle: 16B-block blkL = blkS ^
// ((row>>1)&3), applied inverse on the global SOURCE and on ds_read (rule #21)
// -> 2-way banks on frag reads (free), gload_lds dest stays linear.
// EPI: 0 bf16; 1 +res f32; 2 +bias gelu bf16; 3 +bias +res f32
template <int K, int EPI>
__device__ __forceinline__ void gemm_ring(
    const bf16* __restrict__ A, const bf16* __restrict__ Bw,
    int N, bf16* __restrict__ Cb, float* __restrict__ Cf,
    const float* __restrict__ bias, const float* __restrict__ res)
{
  constexpr int NSTEP = K / 32;
  __shared__ bf16 As[3][2048];
  __shared__ bf16 Bs[3][2048];
  const int tid = threadIdx.x;
  const int lane = tid & 63, wid = tid >> 6;
  const int wm = wid >> 1, wn = wid & 1;
  const int l15 = lane & 15, kg = lane >> 4;
  const int row0 = blockIdx.x * 64, col0 = blockIdx.y * 64;

  // staging: chunk c = tid -> LDS byte c*16 (linear; wave-uniform base+lane*16).
  // row = c>>2, LDS block blkL = c&3; source block blkS = blkL ^ ((row>>1)&3).
  const int srow = tid >> 2;
  const int scol = ((tid & 3) ^ ((srow >> 1) & 3)) * 8;
  const bf16* gA = A + (size_t)(row0 + srow) * K + scol;
  const bf16* gB = Bw + (size_t)(col0 + srow) * K + scol;
  char* const lA = (char*)&As[0][0] + wid * 1024;  // +buf*4096
  char* const lB = (char*)&Bs[0][0] + wid * 1024;

#define STG(buf, kstep)                      \
  {                                          \
    gload16(gA + (kstep) * 32, lA + (buf) * 4096); \
    gload16(gB + (kstep) * 32, lB + (buf) * 4096); \
  }

  f32x4 acc[2][2];
#pragma unroll
  for (int m = 0; m < 2; ++m)
#pragma unroll
    for (int n = 0; n < 2; ++n) acc[m][n] = (f32x4){0.f, 0.f, 0.f, 0.f};

  STG(0, 0);
  STG(1, 1);
  asm volatile("s_waitcnt vmcnt(2)" ::: "memory");  // stage 0 landed; stage 1 in flight
  __builtin_amdgcn_s_barrier();
  __builtin_amdgcn_sched_barrier(0);

#pragma unroll
  for (int t = 0; t < NSTEP; ++t) {
    if (t + 2 < NSTEP) STG((t + 2) % 3, t + 2);
    const char* pa = (const char*)&As[t % 3][0];
    const char* pb = (const char*)&Bs[t % 3][0];
    bf16x8 af[2], bf[2];
#pragma unroll
    for (int m = 0; m < 2; ++m) {
      const int r = wm * 32 + m * 16 + l15;
      af[m] = *(const bf16x8*)(pa + r * 64 + ((kg ^ ((r >> 1) & 3)) << 4));
    }
#pragma unroll
    for (int n = 0; n < 2; ++n) {
      const int r = wn * 32 + n * 16 + l15;
      bf[n] = *(const bf16x8*)(pb + r * 64 + ((kg ^ ((r >> 1) & 3)) << 4));
    }
#pragma unroll
    for (int m = 0; m < 2; ++m)
#pragma unroll
      for (int n = 0; n < 2; ++n)
        acc[m][n] = __builtin_amdgcn_mfma_f32_16x16x32_bf16(af[m], bf[n], acc[m][n], 0, 0, 0);
    if (t + 1 < NSTEP) {
      if (t + 2 < NSTEP)
        asm volatile("s_waitcnt vmcnt(2)" ::: "memory");  // stage t+1 landed, t+2 stays in flight
      else
        asm volatile("s_waitcnt vmcnt(0)" ::: "memory");  // final stage landed
      __builtin_amdgcn_s_barrier();
      __builtin_amdgcn_sched_barrier(0);
    }
  }
#undef STG

  const int orow = row0 + wm * 32, ocol = col0 + wn * 32;
#pragma unroll
  for (int m = 0; m < 2; ++m) {
#pragma unroll
    for (int n = 0; n < 2; ++n) {
#pragma unroll
      for (int e = 0; e < 4; ++e) {
        const int rr = orow + m * 16 + kg * 4 + e;   // C/D: row=(lane>>4)*4+reg
        const int cc = ocol + n * 16 + l15;          //      col=lane&15
        const float v = acc[m][n][e];
        const size_t oi = (size_t)rr * N + cc;
        if constexpr (EPI == 0) {
          Cb[oi] = (bf16)v;
        } else if constexpr (EPI == 1) {
          Cf[oi] = v + res[oi];
        } else if constexpr (EPI == 2) {
          float t2 = v + bias[cc];
          Cb[oi] = (bf16)(0.5f * t2 * (1.f + erff(t2 * 0.70710678118654752f)));
        } else {
          Cf[oi] = v + bias[cc] + res[oi];
        }
      }
    }
  }
}

// named wrappers (unique profiler rows)
__global__ __launch_bounds__(256) void gemm_qkv(
    const bf16* __restrict__ A, const bf16* __restrict__ Bw,
    bf16* __restrict__ Cb)
{
  gemm_ring<512, 0>(A, Bw, QKV_LD, Cb, nullptr, nullptr, nullptr);
}
__global__ __launch_bounds__(256) void gemm_oproj(
    const bf16* __restrict__ A, const bf16* __restrict__ Bw,
    float* __restrict__ Cf, const float* __restrict__ res)
{
  gemm_ring<512, 1>(A, Bw, 512, nullptr, Cf, nullptr, res);
}
__global__ __launch_bounds__(256) void gemm_mlp1(
    const bf16* __restrict__ A, const bf16* __restrict__ Bw,
    bf16* __restrict__ Cb, const float* __restrict__ bias)
{
  gemm_ring<512, 2>(A, Bw, 1024, Cb, nullptr, bias, nullptr);
}
__global__ __launch_bounds__(256) void gemm_mlp2(
    const bf16* __restrict__ A, const bf16* __restrict__ Bw,
    float* __restrict__ Cf, const float* __restrict__ bias,
    const float* __restrict__ res)
{
  gemm_ring<1024, 3>(A, Bw, 512, nullptr, Cf, bias, res);
}

// ---------------- sliding-window causal attention (r5-proven) ----------------
__global__ __launch_bounds__(256) void attn_kernel(
    const bf16* __restrict__ QKV, bf16* __restrict__ Og)
{
  constexpr int STK = 72;
  constexpr int STP = 136;
  __shared__ bf16 Ks[128][STK];
  __shared__ bf16 Qs[64][STK];
  __shared__ bf16 Vt[64][STP];
  __shared__ bf16 Ps[4][16][STP];
  const int tid = threadIdx.x;
  const int qt = blockIdx.x, bh = blockIdx.y;
  const int b = bh >> 3, h = bh & 7;
  const int q0 = qt * 64;
  const int j0 = q0 - 63;
  const size_t baseQ = (size_t)b * LD_L * QKV_LD + h * HD;
  const size_t baseK = baseQ + 512;
  const size_t baseV = baseQ + 1024;
  const size_t baseO = (size_t)b * LD_L * LD_D + h * HD;

  for (int c = tid; c < 128 * 8; c += 256) {
    const int r = c >> 3, d0 = (c & 7) * 8;
    const int j = j0 + r;
    u32x4 kv = (u32x4){0u, 0u, 0u, 0u};
    bf16x8 vv = (bf16x8)(__bf16)0.f;
    if (j >= 0 && j < LD_L) {
      kv = *(const u32x4*)(QKV + baseK + (size_t)j * QKV_LD + d0);
      vv = *(const bf16x8*)(QKV + baseV + (size_t)j * QKV_LD + d0);
    }
    *(u32x4*)(&Ks[r][d0]) = kv;
#pragma unroll
    for (int dd = 0; dd < 8; ++dd) Vt[d0 + dd][r] = vv[dd];
  }
  for (int c = tid; c < 64 * 8; c += 256) {
    const int r = c >> 3, d0 = (c & 7) * 8;
    *(u32x4*)(&Qs[r][d0]) =
        *(const u32x4*)(QKV + baseQ + (size_t)(q0 + r) * QKV_LD + d0);
  }
  __syncthreads();

  const int lane = tid & 63, wid = tid >> 6;
  const int l15 = lane & 15, kg = lane >> 4;
  const int klo = 63 - q0;

  bf16x8 qf[2];
#pragma unroll
  for (int kk = 0; kk < 2; ++kk)
    qf[kk] = *(const bf16x8*)(&Qs[wid * 16 + l15][kk * 32 + kg * 8]);
  f32x4 s[8];
#pragma unroll
  for (int n = 0; n < 8; ++n) s[n] = (f32x4){0.f, 0.f, 0.f, 0.f};
#pragma unroll
  for (int kk = 0; kk < 2; ++kk)
#pragma unroll
    for (int n = 0; n < 8; ++n) {
      bf16x8 kf = *(const bf16x8*)(&Ks[n * 16 + l15][kk * 32 + kg * 8]);
      s[n] = __builtin_amdgcn_mfma_f32_16x16x32_bf16(qf[kk], kf, s[n], 0, 0, 0);
    }

  float p[8][4];
  float mx[4], sm[4];
#pragma unroll
  for (int e = 0; e < 4; ++e) { mx[e] = -INFINITY; sm[e] = 0.f; }
#pragma unroll
  for (int n = 0; n < 8; ++n) {
    const int k = n * 16 + l15;
#pragma unroll
    for (int e = 0; e < 4; ++e) {
      const int qi = wid * 16 + kg * 4 + e;
      const bool ok = (k >= qi) & (k <= qi + 63) & (k >= klo);
      float sv = ok ? s[n][e] * 0.125f : -INFINITY;
      p[n][e] = sv;
      mx[e] = fmaxf(mx[e], sv);
    }
  }
#pragma unroll
  for (int off = 8; off; off >>= 1)
#pragma unroll
    for (int e = 0; e < 4; ++e) mx[e] = fmaxf(mx[e], __shfl_xor(mx[e], off));
#pragma unroll
  for (int n = 0; n < 8; ++n)
#pragma unroll
    for (int e = 0; e < 4; ++e) {
      float pv = (p[n][e] == -INFINITY) ? 0.f : __expf(p[n][e] - mx[e]);
      p[n][e] = pv;
      sm[e] += pv;
    }
#pragma unroll
  for (int off = 8; off; off >>= 1)
#pragma unroll
    for (int e = 0; e < 4; ++e) sm[e] += __shfl_xor(sm[e], off);
  float rs[4];
#pragma unroll
  for (int e = 0; e < 4; ++e) rs[e] = 1.f / sm[e];

#pragma unroll
  for (int n = 0; n < 8; ++n)
#pragma unroll
    for (int e = 0; e < 4; ++e)
      Ps[wid][kg * 4 + e][n * 16 + l15] = (bf16)(p[n][e] * rs[e]);

  f32x4 o[4];
#pragma unroll
  for (int n = 0; n < 4; ++n) o[n] = (f32x4){0.f, 0.f, 0.f, 0.f};
#pragma unroll
  for (int ks = 0; ks < 4; ++ks) {
    bf16x8 pf = *(const bf16x8*)(&Ps[wid][l15][ks * 32 + kg * 8]);
#pragma unroll
    for (int n = 0; n < 4; ++n) {
      bf16x8 vf = *(const bf16x8*)(&Vt[n * 16 + l15][ks * 32 + kg * 8]);
      o[n] = __builtin_amdgcn_mfma_f32_16x16x32_bf16(pf, vf, o[n], 0, 0, 0);
    }
  }

  const int q = q0 + wid * 16 + kg * 4;
#pragma unroll
  for (int n = 0; n < 4; ++n)
#pragma unroll
    for (int e = 0; e < 4; ++e)
      Og[baseO + (size_t)(q + e) * LD_D + n * 16 + l15] = (bf16)o[n][e];
}

// ---------------- launch ----------------
extern "C" void kernel_launch(void* const* d_in, const int* in_sizes, int n_in,
                              void* d_out, int out_size, void* d_ws, size_t ws_size,
                              hipStream_t stream)
{
  const float* query = (const float*)d_in[0];
  const float* ln_g = (const float*)d_in[1];
  const float* ln_b = (const float*)d_in[2];
  const float* wq = (const float*)d_in[3];
  const float* wk = (const float*)d_in[4];
  const float* wv = (const float*)d_in[5];
  const float* wo = (const float*)d_in[6];
  const float* w1 = (const float*)d_in[7];
  const float* b1 = (const float*)d_in[8];
  const float* w2 = (const float*)d_in[9];
  const float* b2 = (const float*)d_in[10];
  float* out = (float*)d_out;

  char* ws = (char*)d_ws;
  bf16* WQKVb = (bf16*)(ws + 0x000000);  // [1536][512] = 1.5MB
  bf16* WOb = (bf16*)(ws + 0x180000);    // 512KB
  bf16* W1b = (bf16*)(ws + 0x200000);    // 1MB
  bf16* W2b = (bf16*)(ws + 0x300000);    // 1MB
  bf16* XLN = (bf16*)(ws + 0x400000);    // 4MB
  bf16* QKVb = (bf16*)(ws + 0x800000);   // [4096][1536] = 12MB
  bf16* ATb = (bf16*)(ws + 0x1400000);   // 4MB
  float* Q2 = (float*)(ws + 0x1800000);  // 8MB
  bf16* YLN = (bf16*)(ws + 0x2000000);   // 4MB
  bf16* Hb = (bf16*)(ws + 0x2400000);    // 8MB (end 44MB)

  prep_kernel<<<3072, 256, 0, stream>>>(
      query, ln_g, ln_b, XLN,
      wq, wk, wv, wo, w1, w2,
      WQKVb, WQKVb + 262144, WQKVb + 524288, WOb, W1b, W2b);
  gemm_qkv<<<dim3(64, 24), 256, 0, stream>>>(XLN, WQKVb, QKVb);
  attn_kernel<<<dim3(32, 16), 256, 0, stream>>>(QKVb, ATb);
  gemm_oproj<<<dim3(64, 8), 256, 0, stream>>>(ATb, WOb, Q2, query);
  ln_kernel<<<1024, 256, 0, stream>>>(Q2, ln_g, ln_b, YLN);
  gemm_mlp1<<<dim3(64, 16), 256, 0, stream>>>(YLN, W1b, Hb, b1);
  gemm_mlp2<<<dim3(64, 8), 256, 0, stream>>>(Hb, W2b, out, b2, Q2);
}